// Round 10
// baseline (1470.114 us; speedup 1.0000x reference)
//
#include <hip/hip_runtime.h>
#include <stdint.h>

#define S_LEN 2048
#define D_DIM 1024
#define NHEAD 16
#define HD    64
#define TOPK  409   // max(1, int(2048*(1.0-0.8)))

typedef unsigned short u16;
typedef __attribute__((ext_vector_type(8))) short bf16x8;
typedef __attribute__((ext_vector_type(4))) float f32x4;
#define MFMA __builtin_amdgcn_mfma_f32_16x16x32_bf16

__device__ __forceinline__ u16 f2b(float f) {                // fp32 -> bf16 RNE
    unsigned u = __float_as_uint(f);
    return (u16)((u + 0x7fffu + ((u >> 16) & 1u)) >> 16);
}
__device__ __forceinline__ float b2f(u16 h) {
    return __uint_as_float(((unsigned)h) << 16);
}

// ---------------------------------------------------------------------------
// fp32 -> bf16 hi/lo split (hi+lo reproduces fp32 to ~2^-16 rel)
// ---------------------------------------------------------------------------
__global__ __launch_bounds__(256, 4)
void split_f32(const float* __restrict__ src, u16* __restrict__ hi,
               u16* __restrict__ lo, int n4)
{
    const int i = blockIdx.x * 256 + threadIdx.x;
    if (i >= n4) return;
    const float4 v = ((const float4*)src)[i];
    const float vv[4] = {v.x, v.y, v.z, v.w};
    u16 h4[4], l4[4];
#pragma unroll
    for (int c = 0; c < 4; ++c) {
        h4[c] = f2b(vv[c]);
        l4[c] = f2b(vv[c] - b2f(h4[c]));
    }
    ((ushort4*)hi)[i] = make_ushort4(h4[0], h4[1], h4[2], h4[3]);
    ((ushort4*)lo)[i] = make_ushort4(l4[0], l4[1], l4[2], l4[3]);
}

// ---------------------------------------------------------------------------
// Fused 4-way weight split: blockIdx.y selects among {Wq,Wk,Wv,Wo}.
// ---------------------------------------------------------------------------
__global__ __launch_bounds__(256, 4)
void split4_f32(const float* __restrict__ s0, const float* __restrict__ s1,
                const float* __restrict__ s2, const float* __restrict__ s3,
                u16* __restrict__ h0, u16* __restrict__ l0,
                u16* __restrict__ h1, u16* __restrict__ l1,
                u16* __restrict__ h2, u16* __restrict__ l2,
                u16* __restrict__ h3, u16* __restrict__ l3, int n4)
{
    const int i = blockIdx.x * 256 + threadIdx.x;
    if (i >= n4) return;
    const int y = blockIdx.y;
    const float* src = (y == 0) ? s0 : (y == 1) ? s1 : (y == 2) ? s2 : s3;
    u16* hi = (y == 0) ? h0 : (y == 1) ? h1 : (y == 2) ? h2 : h3;
    u16* lo = (y == 0) ? l0 : (y == 1) ? l1 : (y == 2) ? l2 : l3;
    const float4 v = ((const float4*)src)[i];
    const float vv[4] = {v.x, v.y, v.z, v.w};
    u16 h4[4], l4[4];
#pragma unroll
    for (int c = 0; c < 4; ++c) {
        h4[c] = f2b(vv[c]);
        l4[c] = f2b(vv[c] - b2f(h4[c]));
    }
    ((ushort4*)hi)[i] = make_ushort4(h4[0], h4[1], h4[2], h4[3]);
    ((ushort4*)lo)[i] = make_ushort4(l4[0], l4[1], l4[2], l4[3]);
}

// ---------------------------------------------------------------------------
// Projection GEMM via 3x bf16-split MFMA: Out = A @ W^T + bias.
// ---------------------------------------------------------------------------
template<int MODE>
__global__ __launch_bounds__(512, 2)
void proj_mfma(const u16* __restrict__ Ahi, const u16* __restrict__ Alo,
               const u16* __restrict__ Whi, const u16* __restrict__ Wlo,
               const float* __restrict__ bias, float* __restrict__ outf,
               u16* __restrict__ o1, u16* __restrict__ o2)
{
    const int t = threadIdx.x, w = t >> 6, l = t & 63;
    const int lq = l & 15, quad = l >> 4;
    const int m0 = blockIdx.y * 128 + (w >> 2) * 64;
    const int n0 = blockIdx.x * 128 + (w & 3) * 32;

    f32x4 acc[4][2];
#pragma unroll
    for (int i = 0; i < 4; ++i)
#pragma unroll
        for (int j = 0; j < 2; ++j) acc[i][j] = (f32x4){0.f, 0.f, 0.f, 0.f};

    const size_t abase = (size_t)(m0 + lq) * D_DIM + quad * 8;
    const size_t bbase = (size_t)(n0 + lq) * D_DIM + quad * 8;

#pragma unroll 2
    for (int k0 = 0; k0 < D_DIM; k0 += 32) {
        bf16x8 ah[4], al[4], bh[2], bl[2];
#pragma unroll
        for (int i = 0; i < 4; ++i) {
            ah[i] = *(const bf16x8*)(Ahi + abase + (size_t)i * 16 * D_DIM + k0);
            al[i] = *(const bf16x8*)(Alo + abase + (size_t)i * 16 * D_DIM + k0);
        }
#pragma unroll
        for (int j = 0; j < 2; ++j) {
            bh[j] = *(const bf16x8*)(Whi + bbase + (size_t)j * 16 * D_DIM + k0);
            bl[j] = *(const bf16x8*)(Wlo + bbase + (size_t)j * 16 * D_DIM + k0);
        }
#pragma unroll
        for (int i = 0; i < 4; ++i)
#pragma unroll
            for (int j = 0; j < 2; ++j) {
                acc[i][j] = MFMA(ah[i], bh[j], acc[i][j], 0, 0, 0);
                acc[i][j] = MFMA(ah[i], bl[j], acc[i][j], 0, 0, 0);
                acc[i][j] = MFMA(al[i], bh[j], acc[i][j], 0, 0, 0);
            }
    }

#pragma unroll
    for (int j = 0; j < 2; ++j) {
        const int n = n0 + j * 16 + lq;
        const float bb = bias[n];
        const int hh = n >> 6, ee = n & 63;
#pragma unroll
        for (int i = 0; i < 4; ++i) {
            const int mb = m0 + i * 16 + quad * 4;
            const int bbm = mb >> 11, ss = mb & 2047;
            if (MODE == 2) {
#pragma unroll
                for (int r = 0; r < 4; ++r)
                    outf[(size_t)(mb + r) * D_DIM + n] = acc[i][j][r] + bb;
            } else if (MODE == 1) {
                ushort4 pk;
                pk.x = f2b(acc[i][j][0] + bb);
                pk.y = f2b(acc[i][j][1] + bb);
                pk.z = f2b(acc[i][j][2] + bb);
                pk.w = f2b(acc[i][j][3] + bb);
                *(ushort4*)(o1 + ((size_t)((bbm * NHEAD + hh) * HD + ee)) * S_LEN + ss) = pk;
            } else {
#pragma unroll
                for (int r = 0; r < 4; ++r) {
                    const float v = acc[i][j][r] + bb;
                    const size_t idx = ((size_t)(bbm * NHEAD + hh) * S_LEN + ss + r) * HD + ee;
                    const u16 h = f2b(v);
                    o1[idx] = h;
                    o2[idx] = f2b(v - b2f(h));
                }
            }
        }
    }
}

// ---------------------------------------------------------------------------
// Attention, QBLK=8 row-ownership, NATURAL register allocation.
// Block = 512 thr (8 waves) owns (b, 8 q-rows), loops 16 heads. Grid 512.
// LDS ~70 KB so TWO blocks/CU fit if the natural VGPR+AGPR total is <=128
// (R8's natural was 120 with twice this array state). NO forced register
// cap: __launch_bounds__(512,2) -- every forced (512,4) cap spilled acc[16]
// to scratch (R4/R5/R6/R9: VGPR=64, FETCH in the 100s of MB..GB).
// Score/PV MFMA use 16-row fragments with rows 8-15 duplicating 0-7
// (Q and PV A-rows indexed lq&7; duplicate outputs discarded at stores).
// Per head: MFMA scores -> stage fp32 rows 0-7 to LDS (barB) -> wave w owns
// row w (64 lanes, 32 vals/lane in regs): mu/sigma, z-grid round 0, 5
// quadrisection rounds, softmax Z all in-wave (width-64 shuffles, zero
// barriers, identical selection arithmetic; count 409 +/- 1) -> attn bf16
// written in-place to own row slot (barC) -> PV MFMA + pvpart (barD).
// ---------------------------------------------------------------------------
__global__ __launch_bounds__(512, 2)
void attn_mfma(const u16* __restrict__ Qhi, const u16* __restrict__ Qlo,
               const u16* __restrict__ Khi, const u16* __restrict__ Klo,
               const u16* __restrict__ Vt,  const float* __restrict__ temp,
               u16* __restrict__ HOhi, u16* __restrict__ HOlo,
               float* __restrict__ avg)
{
    // fp32 scores [8][2060]; attn bf16 overlaid in-place in each row's slot
    // (row slot = 8240 B; attn row = first 4096 B of own slot).
    __shared__ __align__(16) float sLds[8 * 2060];    // 65,920 B
    __shared__ float pvpart[4 * 16 * 16];             // 4,096 B

    const int t = threadIdx.x, w = t >> 6, l = t & 63;
    const int lq = l & 15, quad = l >> 4;
    const int b  = blockIdx.x >> 8;
    const int q0 = (blockIdx.x & 255) << 3;

    float avgreg[32];
#pragma unroll
    for (int i = 0; i < 32; ++i) avgreg[i] = 0.f;

#pragma unroll 1
    for (int h = 0; h < NHEAD; ++h) {
        const size_t bh = (size_t)(b * NHEAD + h) * S_LEN;
        const float tscale = 0.125f / fmaxf(temp[h], 0.1f);

        // ---- Q fragments (rows 8-15 duplicate rows 0-7) --------------------
        const u16* qph = Qhi + (bh + q0 + (lq & 7)) * HD + quad * 8;
        const u16* qpl = Qlo + (bh + q0 + (lq & 7)) * HD + quad * 8;
        const bf16x8 qh0 = *(const bf16x8*)qph;
        const bf16x8 qh1 = *(const bf16x8*)(qph + 32);
        const bf16x8 ql0 = *(const bf16x8*)qpl;
        const bf16x8 ql1 = *(const bf16x8*)(qpl + 32);

        // ---- scores over this wave's 256-col chunk -------------------------
        f32x4 acc[16];
        const u16* kph = Khi + (bh + w * 256 + lq) * HD + quad * 8;
        const u16* kpl = Klo + (bh + w * 256 + lq) * HD + quad * 8;
#pragma unroll
        for (int tt = 0; tt < 16; ++tt) {
            const bf16x8 k0 = *(const bf16x8*)(kph + tt * 16 * HD);
            const bf16x8 k1 = *(const bf16x8*)(kph + tt * 16 * HD + 32);
            const bf16x8 m0 = *(const bf16x8*)(kpl + tt * 16 * HD);
            const bf16x8 m1 = *(const bf16x8*)(kpl + tt * 16 * HD + 32);
            f32x4 a = {0.f, 0.f, 0.f, 0.f};
            a = MFMA(qh0, k0, a, 0, 0, 0);
            a = MFMA(qh1, k1, a, 0, 0, 0);
            a = MFMA(qh0, m0, a, 0, 0, 0);
            a = MFMA(qh1, m1, a, 0, 0, 0);
            a = MFMA(ql0, k0, a, 0, 0, 0);
            a = MFMA(ql1, k1, a, 0, 0, 0);
            acc[tt] = a * tscale;
        }

        // ---- stage fp32 scores, valid rows 0-7 only (quad<2) ---------------
        if (quad < 2) {
#pragma unroll
            for (int tt = 0; tt < 16; ++tt)
#pragma unroll
                for (int r = 0; r < 4; ++r)
                    sLds[(quad * 4 + r) * 2060 + w * 256 + tt * 16 + lq] = acc[tt][r];
        }
        __syncthreads();   // barB: all scores staged (prev PV ended at barD)

        // ---- row ownership: wave w owns row w; lane l cols {2l+128j} -------
        float s[32];
        {
            const float* srow = sLds + (size_t)w * 2060 + 2 * l;
#pragma unroll
            for (int j = 0; j < 16; ++j) {
                const float2 p = *(const float2*)(srow + 128 * j);
                s[2 * j]     = p.x;
                s[2 * j + 1] = p.y;
            }
        }

        // ---- mean / sigma (in-wave, width-64 reduce) -----------------------
        float s1 = 0.f, s2 = 0.f;
#pragma unroll
        for (int j = 0; j < 32; ++j) { s1 += s[j]; s2 = __fmaf_rn(s[j], s[j], s2); }
#pragma unroll
        for (int off = 1; off < 64; off <<= 1) {
            s1 += __shfl_xor(s1, off, 64);
            s2 += __shfl_xor(s2, off, 64);
        }
        const float mu = s1 * (1.f / 2048.f);
        const float va = s2 * (1.f / 2048.f) - mu * mu;
        const float sg = sqrtf(fmaxf(va, 0.f));

        // ---- round 0: z-grid {0.55..1.15} + out-of-bracket fallback --------
        float lo, hi;
        {
            float th[5];
            int c[5];
#pragma unroll
            for (int i = 0; i < 5; ++i) {
                th[i] = __fmaf_rn(sg, 0.55f + 0.15f * (float)i, mu);
                c[i] = 0;
            }
#pragma unroll
            for (int j = 0; j < 32; ++j) {
                const float v = s[j];
#pragma unroll
                for (int i = 0; i < 5; ++i) c[i] += (v >= th[i]) ? 1 : 0;
            }
#pragma unroll
            for (int off = 1; off < 64; off <<= 1)
#pragma unroll
                for (int i = 0; i < 5; ++i) c[i] += __shfl_xor(c[i], off, 64);
            if (c[0] < TOPK) {
                lo = __fmaf_rn(sg, -6.f, mu);
                hi = th[0];
            } else if (c[4] >= TOPK) {
                lo = th[4];
                hi = __fmaf_rn(sg, 6.f, mu);
            } else {
                int bi = 0;
#pragma unroll
                for (int j = 1; j < 4; ++j) if (c[j] >= TOPK) bi = j;
                lo = th[bi];
                hi = th[bi + 1];
            }
        }

        // ---- 5 quadrisection refine rounds (in-wave, no barriers) ----------
#pragma unroll 1
        for (int rd = 0; rd < 5; ++rd) {
            const float w4 = __fmul_rn(__fsub_rn(hi, lo), 0.25f);
            const float t1 = __fmaf_rn(w4, 1.f, lo);
            const float t2 = __fmaf_rn(w4, 2.f, lo);
            const float t3 = __fmaf_rn(w4, 3.f, lo);
            int d0 = 0, d1 = 0, d2 = 0;
#pragma unroll
            for (int j = 0; j < 32; ++j) {
                const float v = s[j];
                d0 += (v >= t1) ? 1 : 0;
                d1 += (v >= t2) ? 1 : 0;
                d2 += (v >= t3) ? 1 : 0;
            }
#pragma unroll
            for (int off = 1; off < 64; off <<= 1) {
                d0 += __shfl_xor(d0, off, 64);
                d1 += __shfl_xor(d1, off, 64);
                d2 += __shfl_xor(d2, off, 64);
            }
            if (d2 >= TOPK)      { lo = t3; }
            else if (d1 >= TOPK) { lo = t2; hi = t3; }
            else if (d0 >= TOPK) { lo = t1; hi = t2; }
            else                 { hi = t1; }
        }

        // ---- sparse softmax (|s| small: raw exp is safe) -------------------
        const float kth = lo;
        float zp = 0.f;
#pragma unroll
        for (int j = 0; j < 32; ++j) {
            const float e = (s[j] >= kth) ? __expf(s[j]) : 0.f;
            s[j] = e;
            zp += e;
        }
#pragma unroll
        for (int off = 1; off < 64; off <<= 1) zp += __shfl_xor(zp, off, 64);
        const float zi = 1.f / zp;

        // ---- normalize, accumulate avg, write attn bf16 in-place -----------
        {
            u16* arow = (u16*)(sLds + (size_t)w * 2060);
#pragma unroll
            for (int j = 0; j < 16; ++j) {
                const float a0 = s[2 * j] * zi;
                const float a1 = s[2 * j + 1] * zi;
                avgreg[2 * j]     += a0;
                avgreg[2 * j + 1] += a1;
                const unsigned pk = (unsigned)f2b(a0) | ((unsigned)f2b(a1) << 16);
                *(unsigned*)(arow + 2 * l + 128 * j) = pk;
            }
        }
        __syncthreads();   // barC: attn rows complete

        // ---- PV: wave w -> e-tile (w&3), j-half (w>>2); A rows lq&7 --------
        const int et = w & 3, jh = w >> 2;
        const u16* vb = Vt + ((size_t)(b * NHEAD + h) * HD + et * 16 + lq) * S_LEN
                        + jh * 1024 + quad * 8;
        const u16* ab = (const u16*)sLds + (size_t)(lq & 7) * 4120 + jh * 1024 + quad * 8;
        f32x4 pv = {0.f, 0.f, 0.f, 0.f};
#pragma unroll 8
        for (int st = 0; st < 32; ++st) {
            const bf16x8 af = *(const bf16x8*)(ab + st * 32);
            const bf16x8 vf = *(const bf16x8*)(vb + st * 32);
            pv = MFMA(af, vf, pv, 0, 0, 0);
        }
        if (w >= 4) {
#pragma unroll
            for (int r = 0; r < 4; ++r)
                pvpart[(et * 16 + quad * 4 + r) * 16 + lq] = pv[r];
        }
        __syncthreads();   // barD: pvpart ready AND all attn/PV reads done
        if (w < 4 && quad < 2) {   // valid output rows 0-7 only
#pragma unroll
            for (int r = 0; r < 4; ++r) {
                const float v = pv[r] + pvpart[(et * 16 + quad * 4 + r) * 16 + lq];
                const size_t idx =
                    ((size_t)(b * S_LEN + q0 + quad * 4 + r)) * D_DIM + h * HD + et * 16 + lq;
                const u16 hv = f2b(v);
                HOhi[idx] = hv;
                HOlo[idx] = f2b(v - b2f(hv));
            }
        }
    } // heads

    // ---- avg_attention = mean over heads (own row w, cols 2l+128j) ---------
    float* avrow = avg + ((size_t)(b * S_LEN + q0 + w)) * S_LEN + 2 * l;
#pragma unroll
    for (int j = 0; j < 16; ++j) {
        float2 o;
        o.x = avgreg[2 * j]     * (1.f / NHEAD);
        o.y = avgreg[2 * j + 1] * (1.f / NHEAD);
        *(float2*)(avrow + 128 * j) = o;
    }
}

// ---------------------------------------------------------------------------
extern "C" void kernel_launch(void* const* d_in, const int* in_sizes, int n_in,
                              void* d_out, int out_size, void* d_ws, size_t ws_size,
                              hipStream_t stream)
{
    const float* x    = (const float*)d_in[0];
    const float* Wq   = (const float*)d_in[1];
    const float* bq   = (const float*)d_in[2];
    const float* Wk   = (const float*)d_in[3];
    const float* bk   = (const float*)d_in[4];
    const float* Wv   = (const float*)d_in[5];
    const float* bv   = (const float*)d_in[6];
    const float* Wo   = (const float*)d_in[7];
    const float* bo   = (const float*)d_in[8];
    const float* temp = (const float*)d_in[9];
    float* out = (float*)d_out;

    const int B = in_sizes[0] / (S_LEN * D_DIM);   // 2
    const int M = B * S_LEN;                       // 4096
    const size_t NQ = (size_t)M * D_DIM;
    const size_t NW = (size_t)D_DIM * D_DIM;

    u16* Qhi = (u16*)d_ws;
    u16* Qlo = Qhi + NQ;
    u16* Khi = Qlo + NQ;
    u16* Klo = Khi + NQ;
    u16* Vt  = Klo + NQ;
    u16* Xhi = Vt  + NQ;   // reused as HOhi after QKV GEMMs
    u16* Xlo = Xhi + NQ;   // reused as HOlo
    u16* Wqh = Xlo + NQ;
    u16* Wql = Wqh + NW;
    u16* Wkh = Wql + NW;
    u16* Wkl = Wkh + NW;
    u16* Wvh = Wkl + NW;
    u16* Wvl = Wvh + NW;
    u16* Woh = Wvl + NW;
    u16* Wol = Woh + NW;
    float* avg = out + NQ;

    const int n4x = (int)(NQ / 4), n4w = (int)(NW / 4);
    split_f32<<<(n4x + 255) / 256, 256, 0, stream>>>(x, Xhi, Xlo, n4x);
    split4_f32<<<dim3((n4w + 255) / 256, 4), 256, 0, stream>>>(
        Wq, Wk, Wv, Wo, Wqh, Wql, Wkh, Wkl, Wvh, Wvl, Woh, Wol, n4w);

    dim3 gg(D_DIM / 128, M / 128, 1);
    proj_mfma<0><<<gg, 512, 0, stream>>>(Xhi, Xlo, Wqh, Wql, bq, nullptr, Qhi, Qlo);
    proj_mfma<0><<<gg, 512, 0, stream>>>(Xhi, Xlo, Wkh, Wkl, bk, nullptr, Khi, Klo);
    proj_mfma<1><<<gg, 512, 0, stream>>>(Xhi, Xlo, Wvh, Wvl, bv, nullptr, Vt, nullptr);

    attn_mfma<<<dim3(M / 8), 512, 0, stream>>>(Qhi, Qlo, Khi, Klo, Vt, temp,
                                               Xhi, Xlo, avg);

    proj_mfma<2><<<gg, 512, 0, stream>>>(Xhi, Xlo, Woh, Wol, bo, out, nullptr, nullptr);
}

// Round 11
// 1461.725 us; speedup vs baseline: 1.0057x; 1.0057x over previous
//
#include <hip/hip_runtime.h>
#include <stdint.h>

#define S_LEN 2048
#define D_DIM 1024
#define NHEAD 16
#define HD    64
#define TOPK  409   // max(1, int(2048*(1.0-0.8)))

typedef unsigned short u16;
typedef __attribute__((ext_vector_type(8))) short bf16x8;
typedef __attribute__((ext_vector_type(4))) float f32x4;
#define MFMA __builtin_amdgcn_mfma_f32_16x16x32_bf16

__device__ __forceinline__ u16 f2b(float f) {                // fp32 -> bf16 RNE
    unsigned u = __float_as_uint(f);
    return (u16)((u + 0x7fffu + ((u >> 16) & 1u)) >> 16);
}
__device__ __forceinline__ float b2f(u16 h) {
    return __uint_as_float(((unsigned)h) << 16);
}

// ---------------------------------------------------------------------------
// fp32 -> bf16 hi/lo split (hi+lo reproduces fp32 to ~2^-16 rel)
// ---------------------------------------------------------------------------
__global__ __launch_bounds__(256, 4)
void split_f32(const float* __restrict__ src, u16* __restrict__ hi,
               u16* __restrict__ lo, int n4)
{
    const int i = blockIdx.x * 256 + threadIdx.x;
    if (i >= n4) return;
    const float4 v = ((const float4*)src)[i];
    const float vv[4] = {v.x, v.y, v.z, v.w};
    u16 h4[4], l4[4];
#pragma unroll
    for (int c = 0; c < 4; ++c) {
        h4[c] = f2b(vv[c]);
        l4[c] = f2b(vv[c] - b2f(h4[c]));
    }
    ((ushort4*)hi)[i] = make_ushort4(h4[0], h4[1], h4[2], h4[3]);
    ((ushort4*)lo)[i] = make_ushort4(l4[0], l4[1], l4[2], l4[3]);
}

// ---------------------------------------------------------------------------
// Fused 4-way weight split: blockIdx.y selects among {Wq,Wk,Wv,Wo}.
// ---------------------------------------------------------------------------
__global__ __launch_bounds__(256, 4)
void split4_f32(const float* __restrict__ s0, const float* __restrict__ s1,
                const float* __restrict__ s2, const float* __restrict__ s3,
                u16* __restrict__ h0, u16* __restrict__ l0,
                u16* __restrict__ h1, u16* __restrict__ l1,
                u16* __restrict__ h2, u16* __restrict__ l2,
                u16* __restrict__ h3, u16* __restrict__ l3, int n4)
{
    const int i = blockIdx.x * 256 + threadIdx.x;
    if (i >= n4) return;
    const int y = blockIdx.y;
    const float* src = (y == 0) ? s0 : (y == 1) ? s1 : (y == 2) ? s2 : s3;
    u16* hi = (y == 0) ? h0 : (y == 1) ? h1 : (y == 2) ? h2 : h3;
    u16* lo = (y == 0) ? l0 : (y == 1) ? l1 : (y == 2) ? l2 : l3;
    const float4 v = ((const float4*)src)[i];
    const float vv[4] = {v.x, v.y, v.z, v.w};
    u16 h4[4], l4[4];
#pragma unroll
    for (int c = 0; c < 4; ++c) {
        h4[c] = f2b(vv[c]);
        l4[c] = f2b(vv[c] - b2f(h4[c]));
    }
    ((ushort4*)hi)[i] = make_ushort4(h4[0], h4[1], h4[2], h4[3]);
    ((ushort4*)lo)[i] = make_ushort4(l4[0], l4[1], l4[2], l4[3]);
}

// ---------------------------------------------------------------------------
// Projection GEMM via 3x bf16-split MFMA: Out = A @ W^T + bias.
// ---------------------------------------------------------------------------
template<int MODE>
__global__ __launch_bounds__(512, 2)
void proj_mfma(const u16* __restrict__ Ahi, const u16* __restrict__ Alo,
               const u16* __restrict__ Whi, const u16* __restrict__ Wlo,
               const float* __restrict__ bias, float* __restrict__ outf,
               u16* __restrict__ o1, u16* __restrict__ o2)
{
    const int t = threadIdx.x, w = t >> 6, l = t & 63;
    const int lq = l & 15, quad = l >> 4;
    const int m0 = blockIdx.y * 128 + (w >> 2) * 64;
    const int n0 = blockIdx.x * 128 + (w & 3) * 32;

    f32x4 acc[4][2];
#pragma unroll
    for (int i = 0; i < 4; ++i)
#pragma unroll
        for (int j = 0; j < 2; ++j) acc[i][j] = (f32x4){0.f, 0.f, 0.f, 0.f};

    const size_t abase = (size_t)(m0 + lq) * D_DIM + quad * 8;
    const size_t bbase = (size_t)(n0 + lq) * D_DIM + quad * 8;

#pragma unroll 2
    for (int k0 = 0; k0 < D_DIM; k0 += 32) {
        bf16x8 ah[4], al[4], bh[2], bl[2];
#pragma unroll
        for (int i = 0; i < 4; ++i) {
            ah[i] = *(const bf16x8*)(Ahi + abase + (size_t)i * 16 * D_DIM + k0);
            al[i] = *(const bf16x8*)(Alo + abase + (size_t)i * 16 * D_DIM + k0);
        }
#pragma unroll
        for (int j = 0; j < 2; ++j) {
            bh[j] = *(const bf16x8*)(Whi + bbase + (size_t)j * 16 * D_DIM + k0);
            bl[j] = *(const bf16x8*)(Wlo + bbase + (size_t)j * 16 * D_DIM + k0);
        }
#pragma unroll
        for (int i = 0; i < 4; ++i)
#pragma unroll
            for (int j = 0; j < 2; ++j) {
                acc[i][j] = MFMA(ah[i], bh[j], acc[i][j], 0, 0, 0);
                acc[i][j] = MFMA(ah[i], bl[j], acc[i][j], 0, 0, 0);
                acc[i][j] = MFMA(al[i], bh[j], acc[i][j], 0, 0, 0);
            }
    }

#pragma unroll
    for (int j = 0; j < 2; ++j) {
        const int n = n0 + j * 16 + lq;
        const float bb = bias[n];
        const int hh = n >> 6, ee = n & 63;
#pragma unroll
        for (int i = 0; i < 4; ++i) {
            const int mb = m0 + i * 16 + quad * 4;
            const int bbm = mb >> 11, ss = mb & 2047;
            if (MODE == 2) {
#pragma unroll
                for (int r = 0; r < 4; ++r)
                    outf[(size_t)(mb + r) * D_DIM + n] = acc[i][j][r] + bb;
            } else if (MODE == 1) {
                ushort4 pk;
                pk.x = f2b(acc[i][j][0] + bb);
                pk.y = f2b(acc[i][j][1] + bb);
                pk.z = f2b(acc[i][j][2] + bb);
                pk.w = f2b(acc[i][j][3] + bb);
                *(ushort4*)(o1 + ((size_t)((bbm * NHEAD + hh) * HD + ee)) * S_LEN + ss) = pk;
            } else {
#pragma unroll
                for (int r = 0; r < 4; ++r) {
                    const float v = acc[i][j][r] + bb;
                    const size_t idx = ((size_t)(bbm * NHEAD + hh) * S_LEN + ss + r) * HD + ee;
                    const u16 h = f2b(v);
                    o1[idx] = h;
                    o2[idx] = f2b(v - b2f(h));
                }
            }
        }
    }
}

// ---------------------------------------------------------------------------
// Attention, QBLK=8 row-ownership, TWO-PASS scores (acc[8] = 32 AGPRs).
// R10 showed natural allocation = 88 VGPR + 64 AGPR(acc[16]) = 152 > 128 ->
// only 1 block/CU. Halving the accumulator (each pass covers 1024 cols:
// wave w computes cols p*1024 + w*128..+127, stages to LDS, re-zeros)
// brings the total to ~88+32 = ~120 <= 128 -> hardware can co-schedule TWO
// 8-wave blocks/CU (LDS 70 KB x2 = 140 <= 160 KB). No forced cap (every
// forced cap spilled: R4/R5/R6/R9). K-traffic unchanged; Q frags live in
// regs across both passes; selection math reads LDS rows, bit-identical.
// Per head: 2x(score pass + stage) -> barB -> wave w owns row w (64 lanes,
// 32 vals/lane): mu/sigma, z-grid round 0, 5 quadrisection rounds, softmax
// Z all in-wave -> attn bf16 in-place (barC) -> PV MFMA + pvpart (barD).
// ---------------------------------------------------------------------------
__global__ __launch_bounds__(512, 2)
void attn_mfma(const u16* __restrict__ Qhi, const u16* __restrict__ Qlo,
               const u16* __restrict__ Khi, const u16* __restrict__ Klo,
               const u16* __restrict__ Vt,  const float* __restrict__ temp,
               u16* __restrict__ HOhi, u16* __restrict__ HOlo,
               float* __restrict__ avg)
{
    // fp32 scores [8][2060]; attn bf16 overlaid in-place in each row's slot
    // (row slot = 8240 B; attn row = first 4096 B of own slot).
    __shared__ __align__(16) float sLds[8 * 2060];    // 65,920 B
    __shared__ float pvpart[4 * 16 * 16];             // 4,096 B

    const int t = threadIdx.x, w = t >> 6, l = t & 63;
    const int lq = l & 15, quad = l >> 4;
    const int b  = blockIdx.x >> 8;
    const int q0 = (blockIdx.x & 255) << 3;

    float avgreg[32];
#pragma unroll
    for (int i = 0; i < 32; ++i) avgreg[i] = 0.f;

#pragma unroll 1
    for (int h = 0; h < NHEAD; ++h) {
        const size_t bh = (size_t)(b * NHEAD + h) * S_LEN;
        const float tscale = 0.125f / fmaxf(temp[h], 0.1f);

        // ---- Q fragments (rows 8-15 duplicate rows 0-7) --------------------
        const u16* qph = Qhi + (bh + q0 + (lq & 7)) * HD + quad * 8;
        const u16* qpl = Qlo + (bh + q0 + (lq & 7)) * HD + quad * 8;
        const bf16x8 qh0 = *(const bf16x8*)qph;
        const bf16x8 qh1 = *(const bf16x8*)(qph + 32);
        const bf16x8 ql0 = *(const bf16x8*)qpl;
        const bf16x8 ql1 = *(const bf16x8*)(qpl + 32);

        // ---- scores: two passes of 128 cols/wave with acc[8] ---------------
#pragma unroll 1
        for (int p = 0; p < 2; ++p) {
            f32x4 acc[8];
            const u16* kph = Khi + (bh + p * 1024 + w * 128 + lq) * HD + quad * 8;
            const u16* kpl = Klo + (bh + p * 1024 + w * 128 + lq) * HD + quad * 8;
#pragma unroll
            for (int tt = 0; tt < 8; ++tt) {
                const bf16x8 k0 = *(const bf16x8*)(kph + tt * 16 * HD);
                const bf16x8 k1 = *(const bf16x8*)(kph + tt * 16 * HD + 32);
                const bf16x8 m0 = *(const bf16x8*)(kpl + tt * 16 * HD);
                const bf16x8 m1 = *(const bf16x8*)(kpl + tt * 16 * HD + 32);
                f32x4 a = {0.f, 0.f, 0.f, 0.f};
                a = MFMA(qh0, k0, a, 0, 0, 0);
                a = MFMA(qh1, k1, a, 0, 0, 0);
                a = MFMA(qh0, m0, a, 0, 0, 0);
                a = MFMA(qh1, m1, a, 0, 0, 0);
                a = MFMA(ql0, k0, a, 0, 0, 0);
                a = MFMA(ql1, k1, a, 0, 0, 0);
                acc[tt] = a * tscale;
            }
            // stage valid rows 0-7 only (quad<2)
            if (quad < 2) {
#pragma unroll
                for (int tt = 0; tt < 8; ++tt)
#pragma unroll
                    for (int r = 0; r < 4; ++r)
                        sLds[(quad * 4 + r) * 2060 + p * 1024 + w * 128 + tt * 16 + lq]
                            = acc[tt][r];
            }
        }
        __syncthreads();   // barB: all scores staged (prev PV ended at barD)

        // ---- row ownership: wave w owns row w; lane l cols {2l+128j} -------
        float s[32];
        {
            const float* srow = sLds + (size_t)w * 2060 + 2 * l;
#pragma unroll
            for (int j = 0; j < 16; ++j) {
                const float2 p = *(const float2*)(srow + 128 * j);
                s[2 * j]     = p.x;
                s[2 * j + 1] = p.y;
            }
        }

        // ---- mean / sigma (in-wave, width-64 reduce) -----------------------
        float s1 = 0.f, s2 = 0.f;
#pragma unroll
        for (int j = 0; j < 32; ++j) { s1 += s[j]; s2 = __fmaf_rn(s[j], s[j], s2); }
#pragma unroll
        for (int off = 1; off < 64; off <<= 1) {
            s1 += __shfl_xor(s1, off, 64);
            s2 += __shfl_xor(s2, off, 64);
        }
        const float mu = s1 * (1.f / 2048.f);
        const float va = s2 * (1.f / 2048.f) - mu * mu;
        const float sg = sqrtf(fmaxf(va, 0.f));

        // ---- round 0: z-grid {0.55..1.15} + out-of-bracket fallback --------
        float lo, hi;
        {
            float th[5];
            int c[5];
#pragma unroll
            for (int i = 0; i < 5; ++i) {
                th[i] = __fmaf_rn(sg, 0.55f + 0.15f * (float)i, mu);
                c[i] = 0;
            }
#pragma unroll
            for (int j = 0; j < 32; ++j) {
                const float v = s[j];
#pragma unroll
                for (int i = 0; i < 5; ++i) c[i] += (v >= th[i]) ? 1 : 0;
            }
#pragma unroll
            for (int off = 1; off < 64; off <<= 1)
#pragma unroll
                for (int i = 0; i < 5; ++i) c[i] += __shfl_xor(c[i], off, 64);
            if (c[0] < TOPK) {
                lo = __fmaf_rn(sg, -6.f, mu);
                hi = th[0];
            } else if (c[4] >= TOPK) {
                lo = th[4];
                hi = __fmaf_rn(sg, 6.f, mu);
            } else {
                int bi = 0;
#pragma unroll
                for (int j = 1; j < 4; ++j) if (c[j] >= TOPK) bi = j;
                lo = th[bi];
                hi = th[bi + 1];
            }
        }

        // ---- 5 quadrisection refine rounds (in-wave, no barriers) ----------
#pragma unroll 1
        for (int rd = 0; rd < 5; ++rd) {
            const float w4 = __fmul_rn(__fsub_rn(hi, lo), 0.25f);
            const float t1 = __fmaf_rn(w4, 1.f, lo);
            const float t2 = __fmaf_rn(w4, 2.f, lo);
            const float t3 = __fmaf_rn(w4, 3.f, lo);
            int d0 = 0, d1 = 0, d2 = 0;
#pragma unroll
            for (int j = 0; j < 32; ++j) {
                const float v = s[j];
                d0 += (v >= t1) ? 1 : 0;
                d1 += (v >= t2) ? 1 : 0;
                d2 += (v >= t3) ? 1 : 0;
            }
#pragma unroll
            for (int off = 1; off < 64; off <<= 1) {
                d0 += __shfl_xor(d0, off, 64);
                d1 += __shfl_xor(d1, off, 64);
                d2 += __shfl_xor(d2, off, 64);
            }
            if (d2 >= TOPK)      { lo = t3; }
            else if (d1 >= TOPK) { lo = t2; hi = t3; }
            else if (d0 >= TOPK) { lo = t1; hi = t2; }
            else                 { hi = t1; }
        }

        // ---- sparse softmax (|s| small: raw exp is safe) -------------------
        const float kth = lo;
        float zp = 0.f;
#pragma unroll
        for (int j = 0; j < 32; ++j) {
            const float e = (s[j] >= kth) ? __expf(s[j]) : 0.f;
            s[j] = e;
            zp += e;
        }
#pragma unroll
        for (int off = 1; off < 64; off <<= 1) zp += __shfl_xor(zp, off, 64);
        const float zi = 1.f / zp;

        // ---- normalize, accumulate avg, write attn bf16 in-place -----------
        {
            u16* arow = (u16*)(sLds + (size_t)w * 2060);
#pragma unroll
            for (int j = 0; j < 16; ++j) {
                const float a0 = s[2 * j] * zi;
                const float a1 = s[2 * j + 1] * zi;
                avgreg[2 * j]     += a0;
                avgreg[2 * j + 1] += a1;
                const unsigned pk = (unsigned)f2b(a0) | ((unsigned)f2b(a1) << 16);
                *(unsigned*)(arow + 2 * l + 128 * j) = pk;
            }
        }
        __syncthreads();   // barC: attn rows complete

        // ---- PV: wave w -> e-tile (w&3), j-half (w>>2); A rows lq&7 --------
        const int et = w & 3, jh = w >> 2;
        const u16* vb = Vt + ((size_t)(b * NHEAD + h) * HD + et * 16 + lq) * S_LEN
                        + jh * 1024 + quad * 8;
        const u16* ab = (const u16*)sLds + (size_t)(lq & 7) * 4120 + jh * 1024 + quad * 8;
        f32x4 pv = {0.f, 0.f, 0.f, 0.f};
#pragma unroll 8
        for (int st = 0; st < 32; ++st) {
            const bf16x8 af = *(const bf16x8*)(ab + st * 32);
            const bf16x8 vf = *(const bf16x8*)(vb + st * 32);
            pv = MFMA(af, vf, pv, 0, 0, 0);
        }
        if (w >= 4) {
#pragma unroll
            for (int r = 0; r < 4; ++r)
                pvpart[(et * 16 + quad * 4 + r) * 16 + lq] = pv[r];
        }
        __syncthreads();   // barD: pvpart ready AND all attn/PV reads done
        if (w < 4 && quad < 2) {   // valid output rows 0-7 only
#pragma unroll
            for (int r = 0; r < 4; ++r) {
                const float v = pv[r] + pvpart[(et * 16 + quad * 4 + r) * 16 + lq];
                const size_t idx =
                    ((size_t)(b * S_LEN + q0 + quad * 4 + r)) * D_DIM + h * HD + et * 16 + lq;
                const u16 hv = f2b(v);
                HOhi[idx] = hv;
                HOlo[idx] = f2b(v - b2f(hv));
            }
        }
    } // heads

    // ---- avg_attention = mean over heads (own row w, cols 2l+128j) ---------
    float* avrow = avg + ((size_t)(b * S_LEN + q0 + w)) * S_LEN + 2 * l;
#pragma unroll
    for (int j = 0; j < 16; ++j) {
        float2 o;
        o.x = avgreg[2 * j]     * (1.f / NHEAD);
        o.y = avgreg[2 * j + 1] * (1.f / NHEAD);
        *(float2*)(avrow + 128 * j) = o;
    }
}

// ---------------------------------------------------------------------------
extern "C" void kernel_launch(void* const* d_in, const int* in_sizes, int n_in,
                              void* d_out, int out_size, void* d_ws, size_t ws_size,
                              hipStream_t stream)
{
    const float* x    = (const float*)d_in[0];
    const float* Wq   = (const float*)d_in[1];
    const float* bq   = (const float*)d_in[2];
    const float* Wk   = (const float*)d_in[3];
    const float* bk   = (const float*)d_in[4];
    const float* Wv   = (const float*)d_in[5];
    const float* bv   = (const float*)d_in[6];
    const float* Wo   = (const float*)d_in[7];
    const float* bo   = (const float*)d_in[8];
    const float* temp = (const float*)d_in[9];
    float* out = (float*)d_out;

    const int B = in_sizes[0] / (S_LEN * D_DIM);   // 2
    const int M = B * S_LEN;                       // 4096
    const size_t NQ = (size_t)M * D_DIM;
    const size_t NW = (size_t)D_DIM * D_DIM;

    u16* Qhi = (u16*)d_ws;
    u16* Qlo = Qhi + NQ;
    u16* Khi = Qlo + NQ;
    u16* Klo = Khi + NQ;
    u16* Vt  = Klo + NQ;
    u16* Xhi = Vt  + NQ;   // reused as HOhi after QKV GEMMs
    u16* Xlo = Xhi + NQ;   // reused as HOlo
    u16* Wqh = Xlo + NQ;
    u16* Wql = Wqh + NW;
    u16* Wkh = Wql + NW;
    u16* Wkl = Wkh + NW;
    u16* Wvh = Wkl + NW;
    u16* Wvl = Wvh + NW;
    u16* Woh = Wvl + NW;
    u16* Wol = Woh + NW;
    float* avg = out + NQ;

    const int n4x = (int)(NQ / 4), n4w = (int)(NW / 4);
    split_f32<<<(n4x + 255) / 256, 256, 0, stream>>>(x, Xhi, Xlo, n4x);
    split4_f32<<<dim3((n4w + 255) / 256, 4), 256, 0, stream>>>(
        Wq, Wk, Wv, Wo, Wqh, Wql, Wkh, Wkl, Wvh, Wvl, Woh, Wol, n4w);

    dim3 gg(D_DIM / 128, M / 128, 1);
    proj_mfma<0><<<gg, 512, 0, stream>>>(Xhi, Xlo, Wqh, Wql, bq, nullptr, Qhi, Qlo);
    proj_mfma<0><<<gg, 512, 0, stream>>>(Xhi, Xlo, Wkh, Wkl, bk, nullptr, Khi, Klo);
    proj_mfma<1><<<gg, 512, 0, stream>>>(Xhi, Xlo, Wvh, Wvl, bv, nullptr, Vt, nullptr);

    attn_mfma<<<dim3(M / 8), 512, 0, stream>>>(Qhi, Qlo, Khi, Klo, Vt, temp,
                                               Xhi, Xlo, avg);

    proj_mfma<2><<<gg, 512, 0, stream>>>(Xhi, Xlo, Woh, Wol, bo, out, nullptr, nullptr);
}

// Round 12
// 1235.160 us; speedup vs baseline: 1.1902x; 1.1834x over previous
//
#include <hip/hip_runtime.h>
#include <stdint.h>

#define S_LEN 2048
#define D_DIM 1024
#define NHEAD 16
#define HD    64
#define TOPK  409   // max(1, int(2048*(1.0-0.8)))

typedef unsigned short u16;
typedef __attribute__((ext_vector_type(8))) short bf16x8;
typedef __attribute__((ext_vector_type(4))) float f32x4;
#define MFMA __builtin_amdgcn_mfma_f32_16x16x32_bf16

__device__ __forceinline__ u16 f2b(float f) {                // fp32 -> bf16 RNE
    unsigned u = __float_as_uint(f);
    return (u16)((u + 0x7fffu + ((u >> 16) & 1u)) >> 16);
}
__device__ __forceinline__ float b2f(u16 h) {
    return __uint_as_float(((unsigned)h) << 16);
}

// ---------------------------------------------------------------------------
// fp32 -> bf16 hi/lo split (hi+lo reproduces fp32 to ~2^-16 rel)
// ---------------------------------------------------------------------------
__global__ __launch_bounds__(256, 4)
void split_f32(const float* __restrict__ src, u16* __restrict__ hi,
               u16* __restrict__ lo, int n4)
{
    const int i = blockIdx.x * 256 + threadIdx.x;
    if (i >= n4) return;
    const float4 v = ((const float4*)src)[i];
    const float vv[4] = {v.x, v.y, v.z, v.w};
    u16 h4[4], l4[4];
#pragma unroll
    for (int c = 0; c < 4; ++c) {
        h4[c] = f2b(vv[c]);
        l4[c] = f2b(vv[c] - b2f(h4[c]));
    }
    ((ushort4*)hi)[i] = make_ushort4(h4[0], h4[1], h4[2], h4[3]);
    ((ushort4*)lo)[i] = make_ushort4(l4[0], l4[1], l4[2], l4[3]);
}

// ---------------------------------------------------------------------------
// Fused 4-way weight split: blockIdx.y selects among {Wq,Wk,Wv,Wo}.
// ---------------------------------------------------------------------------
__global__ __launch_bounds__(256, 4)
void split4_f32(const float* __restrict__ s0, const float* __restrict__ s1,
                const float* __restrict__ s2, const float* __restrict__ s3,
                u16* __restrict__ h0, u16* __restrict__ l0,
                u16* __restrict__ h1, u16* __restrict__ l1,
                u16* __restrict__ h2, u16* __restrict__ l2,
                u16* __restrict__ h3, u16* __restrict__ l3, int n4)
{
    const int i = blockIdx.x * 256 + threadIdx.x;
    if (i >= n4) return;
    const int y = blockIdx.y;
    const float* src = (y == 0) ? s0 : (y == 1) ? s1 : (y == 2) ? s2 : s3;
    u16* hi = (y == 0) ? h0 : (y == 1) ? h1 : (y == 2) ? h2 : h3;
    u16* lo = (y == 0) ? l0 : (y == 1) ? l1 : (y == 2) ? l2 : l3;
    const float4 v = ((const float4*)src)[i];
    const float vv[4] = {v.x, v.y, v.z, v.w};
    u16 h4[4], l4[4];
#pragma unroll
    for (int c = 0; c < 4; ++c) {
        h4[c] = f2b(vv[c]);
        l4[c] = f2b(vv[c] - b2f(h4[c]));
    }
    ((ushort4*)hi)[i] = make_ushort4(h4[0], h4[1], h4[2], h4[3]);
    ((ushort4*)lo)[i] = make_ushort4(l4[0], l4[1], l4[2], l4[3]);
}

// ---------------------------------------------------------------------------
// Projection GEMM via 3x bf16-split MFMA: Out = A @ W^T + bias.
// ---------------------------------------------------------------------------
template<int MODE>
__global__ __launch_bounds__(512, 2)
void proj_mfma(const u16* __restrict__ Ahi, const u16* __restrict__ Alo,
               const u16* __restrict__ Whi, const u16* __restrict__ Wlo,
               const float* __restrict__ bias, float* __restrict__ outf,
               u16* __restrict__ o1, u16* __restrict__ o2)
{
    const int t = threadIdx.x, w = t >> 6, l = t & 63;
    const int lq = l & 15, quad = l >> 4;
    const int m0 = blockIdx.y * 128 + (w >> 2) * 64;
    const int n0 = blockIdx.x * 128 + (w & 3) * 32;

    f32x4 acc[4][2];
#pragma unroll
    for (int i = 0; i < 4; ++i)
#pragma unroll
        for (int j = 0; j < 2; ++j) acc[i][j] = (f32x4){0.f, 0.f, 0.f, 0.f};

    const size_t abase = (size_t)(m0 + lq) * D_DIM + quad * 8;
    const size_t bbase = (size_t)(n0 + lq) * D_DIM + quad * 8;

#pragma unroll 2
    for (int k0 = 0; k0 < D_DIM; k0 += 32) {
        bf16x8 ah[4], al[4], bh[2], bl[2];
#pragma unroll
        for (int i = 0; i < 4; ++i) {
            ah[i] = *(const bf16x8*)(Ahi + abase + (size_t)i * 16 * D_DIM + k0);
            al[i] = *(const bf16x8*)(Alo + abase + (size_t)i * 16 * D_DIM + k0);
        }
#pragma unroll
        for (int j = 0; j < 2; ++j) {
            bh[j] = *(const bf16x8*)(Whi + bbase + (size_t)j * 16 * D_DIM + k0);
            bl[j] = *(const bf16x8*)(Wlo + bbase + (size_t)j * 16 * D_DIM + k0);
        }
#pragma unroll
        for (int i = 0; i < 4; ++i)
#pragma unroll
            for (int j = 0; j < 2; ++j) {
                acc[i][j] = MFMA(ah[i], bh[j], acc[i][j], 0, 0, 0);
                acc[i][j] = MFMA(ah[i], bl[j], acc[i][j], 0, 0, 0);
                acc[i][j] = MFMA(al[i], bh[j], acc[i][j], 0, 0, 0);
            }
    }

#pragma unroll
    for (int j = 0; j < 2; ++j) {
        const int n = n0 + j * 16 + lq;
        const float bb = bias[n];
        const int hh = n >> 6, ee = n & 63;
#pragma unroll
        for (int i = 0; i < 4; ++i) {
            const int mb = m0 + i * 16 + quad * 4;
            const int bbm = mb >> 11, ss = mb & 2047;
            if (MODE == 2) {
#pragma unroll
                for (int r = 0; r < 4; ++r)
                    outf[(size_t)(mb + r) * D_DIM + n] = acc[i][j][r] + bb;
            } else if (MODE == 1) {
                ushort4 pk;
                pk.x = f2b(acc[i][j][0] + bb);
                pk.y = f2b(acc[i][j][1] + bb);
                pk.z = f2b(acc[i][j][2] + bb);
                pk.w = f2b(acc[i][j][3] + bb);
                *(ushort4*)(o1 + ((size_t)((bbm * NHEAD + hh) * HD + ee)) * S_LEN + ss) = pk;
            } else {
#pragma unroll
                for (int r = 0; r < 4; ++r) {
                    const float v = acc[i][j][r] + bb;
                    const size_t idx = ((size_t)(bbm * NHEAD + hh) * S_LEN + ss + r) * HD + ee;
                    const u16 h = f2b(v);
                    o1[idx] = h;
                    o2[idx] = f2b(v - b2f(h));
                }
            }
        }
    }
}

// ---------------------------------------------------------------------------
// Attention, QBLK=8 row-ownership, TWO-PASS scores (acc[8] = 32 AGPRs),
// __launch_bounds__(512,4): cap the UNIFIED reg budget at 128/wave so two
// 8-wave blocks co-reside per CU (LDS 70 KB x2 = 140 <= 160 KB).
// R11 evidence: with the loose (512,2) budget the allocator parked extra
// arrays in AGPRs (76 arch + ~64 AGPR > 128) -> only 1 block/CU. Unlike the
// failed caps (R4/5/6/9, all acc[16]=64 AGPR squeezing arch to 64 vs a
// >=90-reg working set -> spill), acc[8]=32 leaves 96 arch: score phase
// needs ~90 (avgreg 32 + qfrags 16 + K transients + addrs), selection ~47.
// Spill tripwire: FETCH >> 200 MB / occupancy 24% -> revert to R8.
// Per head: 2x(score pass of 128 cols/wave + stage) -> barB -> wave w owns
// row w (64 lanes, 32 vals/lane): mu/sigma, z-grid round 0, 5 quadrisection
// rounds, softmax Z all in-wave -> attn bf16 in-place (barC) -> PV MFMA +
// pvpart (barD). Selection arithmetic bit-identical (count 409 +/- 1).
// ---------------------------------------------------------------------------
__global__ __launch_bounds__(512, 4)
void attn_mfma(const u16* __restrict__ Qhi, const u16* __restrict__ Qlo,
               const u16* __restrict__ Khi, const u16* __restrict__ Klo,
               const u16* __restrict__ Vt,  const float* __restrict__ temp,
               u16* __restrict__ HOhi, u16* __restrict__ HOlo,
               float* __restrict__ avg)
{
    // fp32 scores [8][2060]; attn bf16 overlaid in-place in each row's slot
    // (row slot = 8240 B; attn row = first 4096 B of own slot).
    __shared__ __align__(16) float sLds[8 * 2060];    // 65,920 B
    __shared__ float pvpart[4 * 16 * 16];             // 4,096 B

    const int t = threadIdx.x, w = t >> 6, l = t & 63;
    const int lq = l & 15, quad = l >> 4;
    const int b  = blockIdx.x >> 8;
    const int q0 = (blockIdx.x & 255) << 3;

    float avgreg[32];
#pragma unroll
    for (int i = 0; i < 32; ++i) avgreg[i] = 0.f;

#pragma unroll 1
    for (int h = 0; h < NHEAD; ++h) {
        const size_t bh = (size_t)(b * NHEAD + h) * S_LEN;
        const float tscale = 0.125f / fmaxf(temp[h], 0.1f);

        // ---- Q fragments (rows 8-15 duplicate rows 0-7) --------------------
        const u16* qph = Qhi + (bh + q0 + (lq & 7)) * HD + quad * 8;
        const u16* qpl = Qlo + (bh + q0 + (lq & 7)) * HD + quad * 8;
        const bf16x8 qh0 = *(const bf16x8*)qph;
        const bf16x8 qh1 = *(const bf16x8*)(qph + 32);
        const bf16x8 ql0 = *(const bf16x8*)qpl;
        const bf16x8 ql1 = *(const bf16x8*)(qpl + 32);

        // ---- scores: two passes of 128 cols/wave with acc[8] ---------------
#pragma unroll 1
        for (int p = 0; p < 2; ++p) {
            f32x4 acc[8];
            const u16* kph = Khi + (bh + p * 1024 + w * 128 + lq) * HD + quad * 8;
            const u16* kpl = Klo + (bh + p * 1024 + w * 128 + lq) * HD + quad * 8;
#pragma unroll
            for (int tt = 0; tt < 8; ++tt) {
                const bf16x8 k0 = *(const bf16x8*)(kph + tt * 16 * HD);
                const bf16x8 k1 = *(const bf16x8*)(kph + tt * 16 * HD + 32);
                const bf16x8 m0 = *(const bf16x8*)(kpl + tt * 16 * HD);
                const bf16x8 m1 = *(const bf16x8*)(kpl + tt * 16 * HD + 32);
                f32x4 a = {0.f, 0.f, 0.f, 0.f};
                a = MFMA(qh0, k0, a, 0, 0, 0);
                a = MFMA(qh1, k1, a, 0, 0, 0);
                a = MFMA(qh0, m0, a, 0, 0, 0);
                a = MFMA(qh1, m1, a, 0, 0, 0);
                a = MFMA(ql0, k0, a, 0, 0, 0);
                a = MFMA(ql1, k1, a, 0, 0, 0);
                acc[tt] = a * tscale;
            }
            // stage valid rows 0-7 only (quad<2)
            if (quad < 2) {
#pragma unroll
                for (int tt = 0; tt < 8; ++tt)
#pragma unroll
                    for (int r = 0; r < 4; ++r)
                        sLds[(quad * 4 + r) * 2060 + p * 1024 + w * 128 + tt * 16 + lq]
                            = acc[tt][r];
            }
        }
        __syncthreads();   // barB: all scores staged (prev PV ended at barD)

        // ---- row ownership: wave w owns row w; lane l cols {2l+128j} -------
        float s[32];
        {
            const float* srow = sLds + (size_t)w * 2060 + 2 * l;
#pragma unroll
            for (int j = 0; j < 16; ++j) {
                const float2 p = *(const float2*)(srow + 128 * j);
                s[2 * j]     = p.x;
                s[2 * j + 1] = p.y;
            }
        }

        // ---- mean / sigma (in-wave, width-64 reduce) -----------------------
        float s1 = 0.f, s2 = 0.f;
#pragma unroll
        for (int j = 0; j < 32; ++j) { s1 += s[j]; s2 = __fmaf_rn(s[j], s[j], s2); }
#pragma unroll
        for (int off = 1; off < 64; off <<= 1) {
            s1 += __shfl_xor(s1, off, 64);
            s2 += __shfl_xor(s2, off, 64);
        }
        const float mu = s1 * (1.f / 2048.f);
        const float va = s2 * (1.f / 2048.f) - mu * mu;
        const float sg = sqrtf(fmaxf(va, 0.f));

        // ---- round 0: z-grid {0.55..1.15} + out-of-bracket fallback --------
        float lo, hi;
        {
            float th[5];
            int c[5];
#pragma unroll
            for (int i = 0; i < 5; ++i) {
                th[i] = __fmaf_rn(sg, 0.55f + 0.15f * (float)i, mu);
                c[i] = 0;
            }
#pragma unroll
            for (int j = 0; j < 32; ++j) {
                const float v = s[j];
#pragma unroll
                for (int i = 0; i < 5; ++i) c[i] += (v >= th[i]) ? 1 : 0;
            }
#pragma unroll
            for (int off = 1; off < 64; off <<= 1)
#pragma unroll
                for (int i = 0; i < 5; ++i) c[i] += __shfl_xor(c[i], off, 64);
            if (c[0] < TOPK) {
                lo = __fmaf_rn(sg, -6.f, mu);
                hi = th[0];
            } else if (c[4] >= TOPK) {
                lo = th[4];
                hi = __fmaf_rn(sg, 6.f, mu);
            } else {
                int bi = 0;
#pragma unroll
                for (int j = 1; j < 4; ++j) if (c[j] >= TOPK) bi = j;
                lo = th[bi];
                hi = th[bi + 1];
            }
        }

        // ---- 5 quadrisection refine rounds (in-wave, no barriers) ----------
#pragma unroll 1
        for (int rd = 0; rd < 5; ++rd) {
            const float w4 = __fmul_rn(__fsub_rn(hi, lo), 0.25f);
            const float t1 = __fmaf_rn(w4, 1.f, lo);
            const float t2 = __fmaf_rn(w4, 2.f, lo);
            const float t3 = __fmaf_rn(w4, 3.f, lo);
            int d0 = 0, d1 = 0, d2 = 0;
#pragma unroll
            for (int j = 0; j < 32; ++j) {
                const float v = s[j];
                d0 += (v >= t1) ? 1 : 0;
                d1 += (v >= t2) ? 1 : 0;
                d2 += (v >= t3) ? 1 : 0;
            }
#pragma unroll
            for (int off = 1; off < 64; off <<= 1) {
                d0 += __shfl_xor(d0, off, 64);
                d1 += __shfl_xor(d1, off, 64);
                d2 += __shfl_xor(d2, off, 64);
            }
            if (d2 >= TOPK)      { lo = t3; }
            else if (d1 >= TOPK) { lo = t2; hi = t3; }
            else if (d0 >= TOPK) { lo = t1; hi = t2; }
            else                 { hi = t1; }
        }

        // ---- sparse softmax (|s| small: raw exp is safe) -------------------
        const float kth = lo;
        float zp = 0.f;
#pragma unroll
        for (int j = 0; j < 32; ++j) {
            const float e = (s[j] >= kth) ? __expf(s[j]) : 0.f;
            s[j] = e;
            zp += e;
        }
#pragma unroll
        for (int off = 1; off < 64; off <<= 1) zp += __shfl_xor(zp, off, 64);
        const float zi = 1.f / zp;

        // ---- normalize, accumulate avg, write attn bf16 in-place -----------
        {
            u16* arow = (u16*)(sLds + (size_t)w * 2060);
#pragma unroll
            for (int j = 0; j < 16; ++j) {
                const float a0 = s[2 * j] * zi;
                const float a1 = s[2 * j + 1] * zi;
                avgreg[2 * j]     += a0;
                avgreg[2 * j + 1] += a1;
                const unsigned pk = (unsigned)f2b(a0) | ((unsigned)f2b(a1) << 16);
                *(unsigned*)(arow + 2 * l + 128 * j) = pk;
            }
        }
        __syncthreads();   // barC: attn rows complete

        // ---- PV: wave w -> e-tile (w&3), j-half (w>>2); A rows lq&7 --------
        const int et = w & 3, jh = w >> 2;
        const u16* vb = Vt + ((size_t)(b * NHEAD + h) * HD + et * 16 + lq) * S_LEN
                        + jh * 1024 + quad * 8;
        const u16* ab = (const u16*)sLds + (size_t)(lq & 7) * 4120 + jh * 1024 + quad * 8;
        f32x4 pv = {0.f, 0.f, 0.f, 0.f};
#pragma unroll 8
        for (int st = 0; st < 32; ++st) {
            const bf16x8 af = *(const bf16x8*)(ab + st * 32);
            const bf16x8 vf = *(const bf16x8*)(vb + st * 32);
            pv = MFMA(af, vf, pv, 0, 0, 0);
        }
        if (w >= 4) {
#pragma unroll
            for (int r = 0; r < 4; ++r)
                pvpart[(et * 16 + quad * 4 + r) * 16 + lq] = pv[r];
        }
        __syncthreads();   // barD: pvpart ready AND all attn/PV reads done
        if (w < 4 && quad < 2) {   // valid output rows 0-7 only
#pragma unroll
            for (int r = 0; r < 4; ++r) {
                const float v = pv[r] + pvpart[(et * 16 + quad * 4 + r) * 16 + lq];
                const size_t idx =
                    ((size_t)(b * S_LEN + q0 + quad * 4 + r)) * D_DIM + h * HD + et * 16 + lq;
                const u16 hv = f2b(v);
                HOhi[idx] = hv;
                HOlo[idx] = f2b(v - b2f(hv));
            }
        }
    } // heads

    // ---- avg_attention = mean over heads (own row w, cols 2l+128j) ---------
    float* avrow = avg + ((size_t)(b * S_LEN + q0 + w)) * S_LEN + 2 * l;
#pragma unroll
    for (int j = 0; j < 16; ++j) {
        float2 o;
        o.x = avgreg[2 * j]     * (1.f / NHEAD);
        o.y = avgreg[2 * j + 1] * (1.f / NHEAD);
        *(float2*)(avrow + 128 * j) = o;
    }
}

// ---------------------------------------------------------------------------
extern "C" void kernel_launch(void* const* d_in, const int* in_sizes, int n_in,
                              void* d_out, int out_size, void* d_ws, size_t ws_size,
                              hipStream_t stream)
{
    const float* x    = (const float*)d_in[0];
    const float* Wq   = (const float*)d_in[1];
    const float* bq   = (const float*)d_in[2];
    const float* Wk   = (const float*)d_in[3];
    const float* bk   = (const float*)d_in[4];
    const float* Wv   = (const float*)d_in[5];
    const float* bv   = (const float*)d_in[6];
    const float* Wo   = (const float*)d_in[7];
    const float* bo   = (const float*)d_in[8];
    const float* temp = (const float*)d_in[9];
    float* out = (float*)d_out;

    const int B = in_sizes[0] / (S_LEN * D_DIM);   // 2
    const int M = B * S_LEN;                       // 4096
    const size_t NQ = (size_t)M * D_DIM;
    const size_t NW = (size_t)D_DIM * D_DIM;

    u16* Qhi = (u16*)d_ws;
    u16* Qlo = Qhi + NQ;
    u16* Khi = Qlo + NQ;
    u16* Klo = Khi + NQ;
    u16* Vt  = Klo + NQ;
    u16* Xhi = Vt  + NQ;   // reused as HOhi after QKV GEMMs
    u16* Xlo = Xhi + NQ;   // reused as HOlo
    u16* Wqh = Xlo + NQ;
    u16* Wql = Wqh + NW;
    u16* Wkh = Wql + NW;
    u16* Wkl = Wkh + NW;
    u16* Wvh = Wkl + NW;
    u16* Wvl = Wvh + NW;
    u16* Woh = Wvl + NW;
    u16* Wol = Woh + NW;
    float* avg = out + NQ;

    const int n4x = (int)(NQ / 4), n4w = (int)(NW / 4);
    split_f32<<<(n4x + 255) / 256, 256, 0, stream>>>(x, Xhi, Xlo, n4x);
    split4_f32<<<dim3((n4w + 255) / 256, 4), 256, 0, stream>>>(
        Wq, Wk, Wv, Wo, Wqh, Wql, Wkh, Wkl, Wvh, Wvl, Woh, Wol, n4w);

    dim3 gg(D_DIM / 128, M / 128, 1);
    proj_mfma<0><<<gg, 512, 0, stream>>>(Xhi, Xlo, Wqh, Wql, bq, nullptr, Qhi, Qlo);
    proj_mfma<0><<<gg, 512, 0, stream>>>(Xhi, Xlo, Wkh, Wkl, bk, nullptr, Khi, Klo);
    proj_mfma<1><<<gg, 512, 0, stream>>>(Xhi, Xlo, Wvh, Wvl, bv, nullptr, Vt, nullptr);

    attn_mfma<<<dim3(M / 8), 512, 0, stream>>>(Qhi, Qlo, Khi, Klo, Vt, temp,
                                               Xhi, Xlo, avg);

    proj_mfma<2><<<gg, 512, 0, stream>>>(Xhi, Xlo, Woh, Wol, bo, out, nullptr, nullptr);
}

// Round 13
// 1085.371 us; speedup vs baseline: 1.3545x; 1.1380x over previous
//
#include <hip/hip_runtime.h>
#include <stdint.h>

#define S_LEN 2048
#define D_DIM 1024
#define NHEAD 16
#define HD    64
#define TOPK  409   // max(1, int(2048*(1.0-0.8)))

typedef unsigned short u16;
typedef __attribute__((ext_vector_type(8))) short bf16x8;
typedef __attribute__((ext_vector_type(4))) float f32x4;
#define MFMA __builtin_amdgcn_mfma_f32_16x16x32_bf16

__device__ __forceinline__ u16 f2b(float f) {                // fp32 -> bf16 RNE
    unsigned u = __float_as_uint(f);
    return (u16)((u + 0x7fffu + ((u >> 16) & 1u)) >> 16);
}
__device__ __forceinline__ float b2f(u16 h) {
    return __uint_as_float(((unsigned)h) << 16);
}

// ---------------------------------------------------------------------------
// fp32 -> bf16 hi/lo split (hi+lo reproduces fp32 to ~2^-16 rel)
// ---------------------------------------------------------------------------
__global__ __launch_bounds__(256, 4)
void split_f32(const float* __restrict__ src, u16* __restrict__ hi,
               u16* __restrict__ lo, int n4)
{
    const int i = blockIdx.x * 256 + threadIdx.x;
    if (i >= n4) return;
    const float4 v = ((const float4*)src)[i];
    const float vv[4] = {v.x, v.y, v.z, v.w};
    u16 h4[4], l4[4];
#pragma unroll
    for (int c = 0; c < 4; ++c) {
        h4[c] = f2b(vv[c]);
        l4[c] = f2b(vv[c] - b2f(h4[c]));
    }
    ((ushort4*)hi)[i] = make_ushort4(h4[0], h4[1], h4[2], h4[3]);
    ((ushort4*)lo)[i] = make_ushort4(l4[0], l4[1], l4[2], l4[3]);
}

// ---------------------------------------------------------------------------
// Fused 4-way weight split: blockIdx.y selects among {Wq,Wk,Wv,Wo}.
// ---------------------------------------------------------------------------
__global__ __launch_bounds__(256, 4)
void split4_f32(const float* __restrict__ s0, const float* __restrict__ s1,
                const float* __restrict__ s2, const float* __restrict__ s3,
                u16* __restrict__ h0, u16* __restrict__ l0,
                u16* __restrict__ h1, u16* __restrict__ l1,
                u16* __restrict__ h2, u16* __restrict__ l2,
                u16* __restrict__ h3, u16* __restrict__ l3, int n4)
{
    const int i = blockIdx.x * 256 + threadIdx.x;
    if (i >= n4) return;
    const int y = blockIdx.y;
    const float* src = (y == 0) ? s0 : (y == 1) ? s1 : (y == 2) ? s2 : s3;
    u16* hi = (y == 0) ? h0 : (y == 1) ? h1 : (y == 2) ? h2 : h3;
    u16* lo = (y == 0) ? l0 : (y == 1) ? l1 : (y == 2) ? l2 : l3;
    const float4 v = ((const float4*)src)[i];
    const float vv[4] = {v.x, v.y, v.z, v.w};
    u16 h4[4], l4[4];
#pragma unroll
    for (int c = 0; c < 4; ++c) {
        h4[c] = f2b(vv[c]);
        l4[c] = f2b(vv[c] - b2f(h4[c]));
    }
    ((ushort4*)hi)[i] = make_ushort4(h4[0], h4[1], h4[2], h4[3]);
    ((ushort4*)lo)[i] = make_ushort4(l4[0], l4[1], l4[2], l4[3]);
}

// ---------------------------------------------------------------------------
// Projection GEMM via 3x bf16-split MFMA: Out = A @ W^T + bias.
// ---------------------------------------------------------------------------
template<int MODE>
__global__ __launch_bounds__(512, 2)
void proj_mfma(const u16* __restrict__ Ahi, const u16* __restrict__ Alo,
               const u16* __restrict__ Whi, const u16* __restrict__ Wlo,
               const float* __restrict__ bias, float* __restrict__ outf,
               u16* __restrict__ o1, u16* __restrict__ o2)
{
    const int t = threadIdx.x, w = t >> 6, l = t & 63;
    const int lq = l & 15, quad = l >> 4;
    const int m0 = blockIdx.y * 128 + (w >> 2) * 64;
    const int n0 = blockIdx.x * 128 + (w & 3) * 32;

    f32x4 acc[4][2];
#pragma unroll
    for (int i = 0; i < 4; ++i)
#pragma unroll
        for (int j = 0; j < 2; ++j) acc[i][j] = (f32x4){0.f, 0.f, 0.f, 0.f};

    const size_t abase = (size_t)(m0 + lq) * D_DIM + quad * 8;
    const size_t bbase = (size_t)(n0 + lq) * D_DIM + quad * 8;

#pragma unroll 2
    for (int k0 = 0; k0 < D_DIM; k0 += 32) {
        bf16x8 ah[4], al[4], bh[2], bl[2];
#pragma unroll
        for (int i = 0; i < 4; ++i) {
            ah[i] = *(const bf16x8*)(Ahi + abase + (size_t)i * 16 * D_DIM + k0);
            al[i] = *(const bf16x8*)(Alo + abase + (size_t)i * 16 * D_DIM + k0);
        }
#pragma unroll
        for (int j = 0; j < 2; ++j) {
            bh[j] = *(const bf16x8*)(Whi + bbase + (size_t)j * 16 * D_DIM + k0);
            bl[j] = *(const bf16x8*)(Wlo + bbase + (size_t)j * 16 * D_DIM + k0);
        }
#pragma unroll
        for (int i = 0; i < 4; ++i)
#pragma unroll
            for (int j = 0; j < 2; ++j) {
                acc[i][j] = MFMA(ah[i], bh[j], acc[i][j], 0, 0, 0);
                acc[i][j] = MFMA(ah[i], bl[j], acc[i][j], 0, 0, 0);
                acc[i][j] = MFMA(al[i], bh[j], acc[i][j], 0, 0, 0);
            }
    }

#pragma unroll
    for (int j = 0; j < 2; ++j) {
        const int n = n0 + j * 16 + lq;
        const float bb = bias[n];
        const int hh = n >> 6, ee = n & 63;
#pragma unroll
        for (int i = 0; i < 4; ++i) {
            const int mb = m0 + i * 16 + quad * 4;
            const int bbm = mb >> 11, ss = mb & 2047;
            if (MODE == 2) {
#pragma unroll
                for (int r = 0; r < 4; ++r)
                    outf[(size_t)(mb + r) * D_DIM + n] = acc[i][j][r] + bb;
            } else if (MODE == 1) {
                ushort4 pk;
                pk.x = f2b(acc[i][j][0] + bb);
                pk.y = f2b(acc[i][j][1] + bb);
                pk.z = f2b(acc[i][j][2] + bb);
                pk.w = f2b(acc[i][j][3] + bb);
                *(ushort4*)(o1 + ((size_t)((bbm * NHEAD + hh) * HD + ee)) * S_LEN + ss) = pk;
            } else {
#pragma unroll
                for (int r = 0; r < 4; ++r) {
                    const float v = acc[i][j][r] + bb;
                    const size_t idx = ((size_t)(bbm * NHEAD + hh) * S_LEN + ss + r) * HD + ee;
                    const u16 h = f2b(v);
                    o1[idx] = h;
                    o2[idx] = f2b(v - b2f(h));
                }
            }
        }
    }
}

// ---------------------------------------------------------------------------
// Attention: ONE 1024-thread block (16 waves) owns (b, 16 q-rows), loops 16
// heads. Occupancy comes from 16 waves = 4/SIMD in a single block (LDS
// ~145 KB, 1 block/CU) -- no duplicated MFMA rows, no extra K re-reads
// (R12's QBLK=8 regression), no barrier storm (R1's regression: this has 3
// barriers/head and zero serialized sections).
// Score: wave w covers cols w*128..+127 with acc[8] (32 AGPRs -- R12 proved
// this body fits a 128-reg/wave cap without spill). All 16 A-rows real.
// Selection: wave w owns row w (64 lanes, 32 vals/lane): mu/sigma, z-grid
// round 0, 5 quadrisection rounds, softmax Z -- all in-wave width-64
// shuffle reductions, bit-identical selection arithmetic (count 409 +/- 1).
// attn bf16 written in-place into own row slot (barC). PV: wave (et=w&3,
// jq=w>>2) computes e-tile et, col-quarter jq (16 K-steps); 3-way pvpart
// combine (barD). HO written bf16 hi/lo.
// ---------------------------------------------------------------------------
__global__ __launch_bounds__(1024, 4)
void attn_mfma(const u16* __restrict__ Qhi, const u16* __restrict__ Qlo,
               const u16* __restrict__ Khi, const u16* __restrict__ Klo,
               const u16* __restrict__ Vt,  const float* __restrict__ temp,
               u16* __restrict__ HOhi, u16* __restrict__ HOlo,
               float* __restrict__ avg)
{
    // fp32 scores [16][2060]; attn bf16 overlaid in-place in each row's slot
    // (row slot = 8240 B; attn row = first 4096 B of own slot).
    __shared__ __align__(16) float sLds[16 * 2060];   // 131,840 B
    __shared__ float pvpart[3][64][17];               // 13,056 B

    const int t = threadIdx.x, w = t >> 6, l = t & 63;
    const int lq = l & 15, quad = l >> 4;
    const int b  = blockIdx.x >> 7;
    const int q0 = (blockIdx.x & 127) << 4;

    float avgreg[32];
#pragma unroll
    for (int i = 0; i < 32; ++i) avgreg[i] = 0.f;

#pragma unroll 1
    for (int h = 0; h < NHEAD; ++h) {
        const size_t bh = (size_t)(b * NHEAD + h) * S_LEN;
        const float tscale = 0.125f / fmaxf(temp[h], 0.1f);

        // ---- Q fragments (all 16 rows real) --------------------------------
        const u16* qph = Qhi + (bh + q0 + lq) * HD + quad * 8;
        const u16* qpl = Qlo + (bh + q0 + lq) * HD + quad * 8;
        const bf16x8 qh0 = *(const bf16x8*)qph;
        const bf16x8 qh1 = *(const bf16x8*)(qph + 32);
        const bf16x8 ql0 = *(const bf16x8*)qpl;
        const bf16x8 ql1 = *(const bf16x8*)(qpl + 32);

        // ---- scores: wave w covers cols w*128..+127, acc[8] ----------------
        f32x4 acc[8];
        const u16* kph = Khi + (bh + w * 128 + lq) * HD + quad * 8;
        const u16* kpl = Klo + (bh + w * 128 + lq) * HD + quad * 8;
#pragma unroll
        for (int tt = 0; tt < 8; ++tt) {
            const bf16x8 k0 = *(const bf16x8*)(kph + tt * 16 * HD);
            const bf16x8 k1 = *(const bf16x8*)(kph + tt * 16 * HD + 32);
            const bf16x8 m0 = *(const bf16x8*)(kpl + tt * 16 * HD);
            const bf16x8 m1 = *(const bf16x8*)(kpl + tt * 16 * HD + 32);
            f32x4 a = {0.f, 0.f, 0.f, 0.f};
            a = MFMA(qh0, k0, a, 0, 0, 0);
            a = MFMA(qh1, k1, a, 0, 0, 0);
            a = MFMA(qh0, m0, a, 0, 0, 0);
            a = MFMA(qh1, m1, a, 0, 0, 0);
            a = MFMA(ql0, k0, a, 0, 0, 0);
            a = MFMA(ql1, k1, a, 0, 0, 0);
            acc[tt] = a * tscale;
        }

        // ---- stage fp32 scores (all rows real) -----------------------------
#pragma unroll
        for (int tt = 0; tt < 8; ++tt)
#pragma unroll
            for (int r = 0; r < 4; ++r)
                sLds[(quad * 4 + r) * 2060 + w * 128 + tt * 16 + lq] = acc[tt][r];
        __syncthreads();   // barB: all scores staged (prev PV ended at barD)

        // ---- row ownership: wave w owns row w; lane l cols {2l+128j} -------
        float s[32];
        {
            const float* srow = sLds + (size_t)w * 2060 + 2 * l;
#pragma unroll
            for (int j = 0; j < 16; ++j) {
                const float2 p = *(const float2*)(srow + 128 * j);
                s[2 * j]     = p.x;
                s[2 * j + 1] = p.y;
            }
        }

        // ---- mean / sigma (in-wave, width-64 reduce) -----------------------
        float s1 = 0.f, s2 = 0.f;
#pragma unroll
        for (int j = 0; j < 32; ++j) { s1 += s[j]; s2 = __fmaf_rn(s[j], s[j], s2); }
#pragma unroll
        for (int off = 1; off < 64; off <<= 1) {
            s1 += __shfl_xor(s1, off, 64);
            s2 += __shfl_xor(s2, off, 64);
        }
        const float mu = s1 * (1.f / 2048.f);
        const float va = s2 * (1.f / 2048.f) - mu * mu;
        const float sg = sqrtf(fmaxf(va, 0.f));

        // ---- round 0: z-grid {0.55..1.15} + out-of-bracket fallback --------
        float lo, hi;
        {
            float th[5];
            int c[5];
#pragma unroll
            for (int i = 0; i < 5; ++i) {
                th[i] = __fmaf_rn(sg, 0.55f + 0.15f * (float)i, mu);
                c[i] = 0;
            }
#pragma unroll
            for (int j = 0; j < 32; ++j) {
                const float v = s[j];
#pragma unroll
                for (int i = 0; i < 5; ++i) c[i] += (v >= th[i]) ? 1 : 0;
            }
#pragma unroll
            for (int off = 1; off < 64; off <<= 1)
#pragma unroll
                for (int i = 0; i < 5; ++i) c[i] += __shfl_xor(c[i], off, 64);
            if (c[0] < TOPK) {
                lo = __fmaf_rn(sg, -6.f, mu);
                hi = th[0];
            } else if (c[4] >= TOPK) {
                lo = th[4];
                hi = __fmaf_rn(sg, 6.f, mu);
            } else {
                int bi = 0;
#pragma unroll
                for (int j = 1; j < 4; ++j) if (c[j] >= TOPK) bi = j;
                lo = th[bi];
                hi = th[bi + 1];
            }
        }

        // ---- 5 quadrisection refine rounds (in-wave, no barriers) ----------
#pragma unroll 1
        for (int rd = 0; rd < 5; ++rd) {
            const float w4 = __fmul_rn(__fsub_rn(hi, lo), 0.25f);
            const float t1 = __fmaf_rn(w4, 1.f, lo);
            const float t2 = __fmaf_rn(w4, 2.f, lo);
            const float t3 = __fmaf_rn(w4, 3.f, lo);
            int d0 = 0, d1 = 0, d2 = 0;
#pragma unroll
            for (int j = 0; j < 32; ++j) {
                const float v = s[j];
                d0 += (v >= t1) ? 1 : 0;
                d1 += (v >= t2) ? 1 : 0;
                d2 += (v >= t3) ? 1 : 0;
            }
#pragma unroll
            for (int off = 1; off < 64; off <<= 1) {
                d0 += __shfl_xor(d0, off, 64);
                d1 += __shfl_xor(d1, off, 64);
                d2 += __shfl_xor(d2, off, 64);
            }
            if (d2 >= TOPK)      { lo = t3; }
            else if (d1 >= TOPK) { lo = t2; hi = t3; }
            else if (d0 >= TOPK) { lo = t1; hi = t2; }
            else                 { hi = t1; }
        }

        // ---- sparse softmax (|s| small: raw exp is safe) -------------------
        const float kth = lo;
        float zp = 0.f;
#pragma unroll
        for (int j = 0; j < 32; ++j) {
            const float e = (s[j] >= kth) ? __expf(s[j]) : 0.f;
            s[j] = e;
            zp += e;
        }
#pragma unroll
        for (int off = 1; off < 64; off <<= 1) zp += __shfl_xor(zp, off, 64);
        const float zi = 1.f / zp;

        // ---- normalize, accumulate avg, write attn bf16 in-place -----------
        {
            u16* arow = (u16*)(sLds + (size_t)w * 2060);
#pragma unroll
            for (int j = 0; j < 16; ++j) {
                const float a0 = s[2 * j] * zi;
                const float a1 = s[2 * j + 1] * zi;
                avgreg[2 * j]     += a0;
                avgreg[2 * j + 1] += a1;
                const unsigned pk = (unsigned)f2b(a0) | ((unsigned)f2b(a1) << 16);
                *(unsigned*)(arow + 2 * l + 128 * j) = pk;
            }
        }
        __syncthreads();   // barC: attn rows complete

        // ---- PV: wave w -> e-tile (w&3), col-quarter (w>>2); 16 K-steps ----
        const int et = w & 3, jq = w >> 2;
        const u16* vb = Vt + ((size_t)(b * NHEAD + h) * HD + et * 16 + lq) * S_LEN
                        + jq * 512 + quad * 8;
        const u16* ab = (const u16*)sLds + (size_t)lq * 4120 + jq * 512 + quad * 8;
        f32x4 pv = {0.f, 0.f, 0.f, 0.f};
#pragma unroll 8
        for (int st = 0; st < 16; ++st) {
            const bf16x8 af = *(const bf16x8*)(ab + st * 32);
            const bf16x8 vf = *(const bf16x8*)(vb + st * 32);
            pv = MFMA(af, vf, pv, 0, 0, 0);
        }
        if (jq > 0) {
#pragma unroll
            for (int r = 0; r < 4; ++r)
                pvpart[jq - 1][et * 16 + quad * 4 + r][lq] = pv[r];
        }
        __syncthreads();   // barD: pvpart ready AND all attn/PV reads done
        if (jq == 0) {
#pragma unroll
            for (int r = 0; r < 4; ++r) {
                const int row = et * 16 + quad * 4 + r;
                const float v = pv[r] + pvpart[0][row][lq] + pvpart[1][row][lq]
                              + pvpart[2][row][lq];
                const size_t idx =
                    ((size_t)(b * S_LEN + q0 + quad * 4 + r)) * D_DIM + h * HD + et * 16 + lq;
                const u16 hv = f2b(v);
                HOhi[idx] = hv;
                HOlo[idx] = f2b(v - b2f(hv));
            }
        }
    } // heads

    // ---- avg_attention = mean over heads (own row w, cols 2l+128j) ---------
    float* avrow = avg + ((size_t)(b * S_LEN + q0 + w)) * S_LEN + 2 * l;
#pragma unroll
    for (int j = 0; j < 16; ++j) {
        float2 o;
        o.x = avgreg[2 * j]     * (1.f / NHEAD);
        o.y = avgreg[2 * j + 1] * (1.f / NHEAD);
        *(float2*)(avrow + 128 * j) = o;
    }
}

// ---------------------------------------------------------------------------
extern "C" void kernel_launch(void* const* d_in, const int* in_sizes, int n_in,
                              void* d_out, int out_size, void* d_ws, size_t ws_size,
                              hipStream_t stream)
{
    const float* x    = (const float*)d_in[0];
    const float* Wq   = (const float*)d_in[1];
    const float* bq   = (const float*)d_in[2];
    const float* Wk   = (const float*)d_in[3];
    const float* bk   = (const float*)d_in[4];
    const float* Wv   = (const float*)d_in[5];
    const float* bv   = (const float*)d_in[6];
    const float* Wo   = (const float*)d_in[7];
    const float* bo   = (const float*)d_in[8];
    const float* temp = (const float*)d_in[9];
    float* out = (float*)d_out;

    const int B = in_sizes[0] / (S_LEN * D_DIM);   // 2
    const int M = B * S_LEN;                       // 4096
    const size_t NQ = (size_t)M * D_DIM;
    const size_t NW = (size_t)D_DIM * D_DIM;

    u16* Qhi = (u16*)d_ws;
    u16* Qlo = Qhi + NQ;
    u16* Khi = Qlo + NQ;
    u16* Klo = Khi + NQ;
    u16* Vt  = Klo + NQ;
    u16* Xhi = Vt  + NQ;   // reused as HOhi after QKV GEMMs
    u16* Xlo = Xhi + NQ;   // reused as HOlo
    u16* Wqh = Xlo + NQ;
    u16* Wql = Wqh + NW;
    u16* Wkh = Wql + NW;
    u16* Wkl = Wkh + NW;
    u16* Wvh = Wkl + NW;
    u16* Wvl = Wvh + NW;
    u16* Woh = Wvl + NW;
    u16* Wol = Woh + NW;
    float* avg = out + NQ;

    const int n4x = (int)(NQ / 4), n4w = (int)(NW / 4);
    split_f32<<<(n4x + 255) / 256, 256, 0, stream>>>(x, Xhi, Xlo, n4x);
    split4_f32<<<dim3((n4w + 255) / 256, 4), 256, 0, stream>>>(
        Wq, Wk, Wv, Wo, Wqh, Wql, Wkh, Wkl, Wvh, Wvl, Woh, Wol, n4w);

    dim3 gg(D_DIM / 128, M / 128, 1);
    proj_mfma<0><<<gg, 512, 0, stream>>>(Xhi, Xlo, Wqh, Wql, bq, nullptr, Qhi, Qlo);
    proj_mfma<0><<<gg, 512, 0, stream>>>(Xhi, Xlo, Wkh, Wkl, bk, nullptr, Khi, Klo);
    proj_mfma<1><<<gg, 512, 0, stream>>>(Xhi, Xlo, Wvh, Wvl, bv, nullptr, Vt, nullptr);

    attn_mfma<<<dim3(M / 16), 1024, 0, stream>>>(Qhi, Qlo, Khi, Klo, Vt, temp,
                                                 Xhi, Xlo, avg);

    proj_mfma<2><<<gg, 512, 0, stream>>>(Xhi, Xlo, Woh, Wol, bo, out, nullptr, nullptr);
}